// Round 7
// baseline (71.343 us; speedup 1.0000x reference)
//
#include <hip/hip_runtime.h>
#include <math.h>

#define NPTS   8192
#define BITS   64
#define NCLS   101
#define TILE   128
#define NT     (NPTS / TILE)            // 64
#define NPAIRS (NT * (NT + 1) / 2)      // 2080
#define WS_CLS (3 * NPAIRS)
#define WS_DGA (4 * NPAIRS)             // diagA dump (ignored by final)
#define WS_DGB (5 * NPAIRS)             // diagB dump (ignored by final)
#define SQH    0.70710678f              // sqrt(0.5): staged h*SQH -> acc = theta

typedef short    bf16x8   __attribute__((ext_vector_type(8)));
typedef unsigned short ushort8v __attribute__((ext_vector_type(8)));
typedef float    f32x16   __attribute__((ext_vector_type(16)));

__device__ __forceinline__ unsigned short f2bf(float f) {
    unsigned int u = __float_as_uint(f);
    u += 0x7FFFu + ((u >> 16) & 1u);     // RNE (inputs finite)
    return (unsigned short)(u >> 16);
}

__device__ __forceinline__ void tile_map(int p, int& ti, int& tj) {
    float disc = (2.0f * NT + 1.0f) * (2.0f * NT + 1.0f) - 8.0f * (float)p;
    ti = (int)(((2.0f * NT + 1.0f) - sqrtf(disc)) * 0.5f);
    if (ti < 0) ti = 0;
    if (ti >= NT) ti = NT - 1;
    while (ti > 0 && (ti * NT - ti * (ti - 1) / 2) > p) ti--;
    while ((ti + 1) * NT - (ti + 1) * ti / 2 <= p) ti++;
    tj = ti + (p - (ti * NT - ti * (ti - 1) / 2));
}

// ---------------------------------------------------------------------------
// PRODUCTION kernel (exact R3 body): fused hash tile + cls rows.
// ---------------------------------------------------------------------------
__global__ __launch_bounds__(256) void hash_cls_kernel(const float* __restrict__ H,
                                                       const float* __restrict__ X,
                                                       const int* __restrict__ tgt,
                                                       double* __restrict__ ws) {
    __shared__ unsigned short As[TILE * BITS];
    __shared__ unsigned short Bs[TILE * BITS];
    __shared__ int tI[TILE];
    __shared__ int tJ[TILE];
    __shared__ float red[16];

    const int tid = threadIdx.x;
    const int p = blockIdx.x;
    int ti, tj; tile_map(p, ti, tj);
    const int i0 = ti * TILE, j0 = tj * TILE;
    const bool diag = (ti == tj);

    if (tid < TILE) { tI[tid] = tgt[i0 + tid]; tJ[tid] = tgt[j0 + tid]; }

#pragma unroll
    for (int it = 0; it < 8; ++it) {
        int idx  = tid + it * 256;
        int half = idx >> 10;
        int lid  = idx & 1023;
        int row  = lid >> 3;
        int c    = lid & 7;
        const float* src = H + (size_t)((half ? j0 : i0) + row) * BITS + c * 8;
        float4 f0 = *(const float4*)src;
        float4 f1 = *(const float4*)(src + 4);
        ushort8v v;
        v[0] = f2bf(f0.x * SQH); v[1] = f2bf(f0.y * SQH);
        v[2] = f2bf(f0.z * SQH); v[3] = f2bf(f0.w * SQH);
        v[4] = f2bf(f1.x * SQH); v[5] = f2bf(f1.y * SQH);
        v[6] = f2bf(f1.z * SQH); v[7] = f2bf(f1.w * SQH);
        unsigned short* dst = half ? Bs : As;
        *(ushort8v*)&dst[row * BITS + ((c ^ (row & 7)) * 8)] = v;
    }
    __syncthreads();

    const int lane = tid & 63, wave = tid >> 6;
    const int wr = wave >> 1, wc = wave & 1;
    const int lrow = lane & 31, hi = lane >> 5;

    f32x16 acc[2][2];
#pragma unroll
    for (int a = 0; a < 2; ++a)
#pragma unroll
        for (int b = 0; b < 2; ++b)
#pragma unroll
            for (int e = 0; e < 16; ++e) acc[a][b][e] = 0.f;

    auto ldfrag = [](const unsigned short* S, int row, int chunk) -> bf16x8 {
        ushort8v r = *(const ushort8v*)&S[row * BITS + ((chunk ^ (row & 7)) * 8)];
        return __builtin_bit_cast(bf16x8, r);
    };

#pragma unroll
    for (int ks = 0; ks < 4; ++ks) {
        const int ch = ks * 2 + hi;
        bf16x8 a0 = ldfrag(As, wr * 64 +      lrow, ch);
        bf16x8 a1 = ldfrag(As, wr * 64 + 32 + lrow, ch);
        bf16x8 b0 = ldfrag(Bs, wc * 64 +      lrow, ch);
        bf16x8 b1 = ldfrag(Bs, wc * 64 + 32 + lrow, ch);
        acc[0][0] = __builtin_amdgcn_mfma_f32_32x32x16_bf16(a0, b0, acc[0][0], 0, 0, 0);
        acc[0][1] = __builtin_amdgcn_mfma_f32_32x32x16_bf16(a0, b1, acc[0][1], 0, 0, 0);
        acc[1][0] = __builtin_amdgcn_mfma_f32_32x32x16_bf16(a1, b0, acc[1][0], 0, 0, 0);
        acc[1][1] = __builtin_amdgcn_mfma_f32_32x32x16_bf16(a1, b1, acc[1][1], 0, 0, 0);
    }

    float s_all = 0.f, s_same = 0.f, t_same = 0.f;
    if (!diag) {
#pragma unroll
        for (int it = 0; it < 2; ++it) {
            int trow[16];
#pragma unroll
            for (int r = 0; r < 16; ++r)
                trow[r] = tI[wr * 64 + it * 32 + (r & 3) + 8 * (r >> 2) + 4 * hi];
#pragma unroll
            for (int jt = 0; jt < 2; ++jt) {
                const int tc = tJ[wc * 64 + jt * 32 + lrow];
                const f32x16& C = it ? (jt ? acc[1][1] : acc[1][0])
                                     : (jt ? acc[0][1] : acc[0][0]);
#pragma unroll
                for (int r = 0; r < 16; ++r) {
                    float a  = C[r];
                    float e  = __expf(a);
                    float lg = __logf(1.0f + e);
                    s_all += lg;
                    float m = (trow[r] == tc) ? 1.0f : 0.0f;
                    s_same = fmaf(m, lg, s_same);
                    t_same = fmaf(m, a,  t_same);
                }
            }
        }
    } else {
#pragma unroll
        for (int it = 0; it < 2; ++it) {
            int trow[16], lrr[16];
#pragma unroll
            for (int r = 0; r < 16; ++r) {
                lrr[r] = wr * 64 + it * 32 + (r & 3) + 8 * (r >> 2) + 4 * hi;
                trow[r] = tI[lrr[r]];
            }
#pragma unroll
            for (int jt = 0; jt < 2; ++jt) {
                const int lc = wc * 64 + jt * 32 + lrow;
                const int tc = tJ[lc];
                const f32x16& C = it ? (jt ? acc[1][1] : acc[1][0])
                                     : (jt ? acc[0][1] : acc[0][0]);
#pragma unroll
                for (int r = 0; r < 16; ++r) {
                    float a  = C[r];
                    float e  = __expf(a);
                    float lg = __logf(1.0f + e);
                    bool v = lc > lrr[r];
                    bool sm = v && (trow[r] == tc);
                    s_all  += v  ? lg : 0.f;
                    s_same += sm ? lg : 0.f;
                    t_same += sm ? a  : 0.f;
                }
            }
        }
    }

#pragma unroll
    for (int d = 32; d > 0; d >>= 1) {
        s_all  += __shfl_xor(s_all,  d, 64);
        s_same += __shfl_xor(s_same, d, 64);
        t_same += __shfl_xor(t_same, d, 64);
    }
    if (lane == 0) { red[wave] = s_all; red[4 + wave] = s_same; red[8 + wave] = t_same; }

    {   // fused cls rows
        const int row = p * 4 + wave;
        float nll = 0.f;
        if (row < NPTS) {
            const float* x = X + (size_t)row * NCLS;
            float x1 = x[lane];
            float x2 = (lane + 64 < NCLS) ? x[lane + 64] : -INFINITY;
            float m = fmaxf(x1, x2);
#pragma unroll
            for (int d = 32; d > 0; d >>= 1) m = fmaxf(m, __shfl_xor(m, d, 64));
            float e = __expf(x1 - m) + ((lane + 64 < NCLS) ? __expf(x2 - m) : 0.f);
#pragma unroll
            for (int d = 32; d > 0; d >>= 1) e += __shfl_xor(e, d, 64);
            if (lane == 0) nll = m + __logf(e) - x[tgt[row]];
        }
        if (lane == 0) red[12 + wave] = nll;
    }
    __syncthreads();
    if (tid == 0) {
        ws[p]              = (double)red[0]  + (double)red[1]  + (double)red[2]  + (double)red[3];
        ws[NPAIRS + p]     = (double)red[4]  + (double)red[5]  + (double)red[6]  + (double)red[7];
        ws[2 * NPAIRS + p] = (double)red[8]  + (double)red[9]  + (double)red[10] + (double)red[11];
        ws[WS_CLS + p]     = (double)red[12] + (double)red[13] + (double)red[14] + (double)red[15];
    }
}

// ---------------------------------------------------------------------------
// DIAGNOSTIC A: identical staging + MFMA + acc-read + reduce; epilogue is a
// plain sum of acc (no trans, no masks, no tgt). Result dumped to unused ws.
// ---------------------------------------------------------------------------
__global__ __launch_bounds__(256) void diagA_kernel(const float* __restrict__ H,
                                                    double* __restrict__ ws) {
    __shared__ unsigned short As[TILE * BITS];
    __shared__ unsigned short Bs[TILE * BITS];
    __shared__ float red[4];

    const int tid = threadIdx.x;
    const int p = blockIdx.x;
    int ti, tj; tile_map(p, ti, tj);
    const int i0 = ti * TILE, j0 = tj * TILE;

#pragma unroll
    for (int it = 0; it < 8; ++it) {
        int idx  = tid + it * 256;
        int half = idx >> 10;
        int lid  = idx & 1023;
        int row  = lid >> 3;
        int c    = lid & 7;
        const float* src = H + (size_t)((half ? j0 : i0) + row) * BITS + c * 8;
        float4 f0 = *(const float4*)src;
        float4 f1 = *(const float4*)(src + 4);
        ushort8v v;
        v[0] = f2bf(f0.x * SQH); v[1] = f2bf(f0.y * SQH);
        v[2] = f2bf(f0.z * SQH); v[3] = f2bf(f0.w * SQH);
        v[4] = f2bf(f1.x * SQH); v[5] = f2bf(f1.y * SQH);
        v[6] = f2bf(f1.z * SQH); v[7] = f2bf(f1.w * SQH);
        unsigned short* dst = half ? Bs : As;
        *(ushort8v*)&dst[row * BITS + ((c ^ (row & 7)) * 8)] = v;
    }
    __syncthreads();

    const int lane = tid & 63, wave = tid >> 6;
    const int wr = wave >> 1, wc = wave & 1;
    const int lrow = lane & 31, hi = lane >> 5;

    f32x16 acc[2][2];
#pragma unroll
    for (int a = 0; a < 2; ++a)
#pragma unroll
        for (int b = 0; b < 2; ++b)
#pragma unroll
            for (int e = 0; e < 16; ++e) acc[a][b][e] = 0.f;

    auto ldfrag = [](const unsigned short* S, int row, int chunk) -> bf16x8 {
        ushort8v r = *(const ushort8v*)&S[row * BITS + ((chunk ^ (row & 7)) * 8)];
        return __builtin_bit_cast(bf16x8, r);
    };

#pragma unroll
    for (int ks = 0; ks < 4; ++ks) {
        const int ch = ks * 2 + hi;
        bf16x8 a0 = ldfrag(As, wr * 64 +      lrow, ch);
        bf16x8 a1 = ldfrag(As, wr * 64 + 32 + lrow, ch);
        bf16x8 b0 = ldfrag(Bs, wc * 64 +      lrow, ch);
        bf16x8 b1 = ldfrag(Bs, wc * 64 + 32 + lrow, ch);
        acc[0][0] = __builtin_amdgcn_mfma_f32_32x32x16_bf16(a0, b0, acc[0][0], 0, 0, 0);
        acc[0][1] = __builtin_amdgcn_mfma_f32_32x32x16_bf16(a0, b1, acc[0][1], 0, 0, 0);
        acc[1][0] = __builtin_amdgcn_mfma_f32_32x32x16_bf16(a1, b0, acc[1][0], 0, 0, 0);
        acc[1][1] = __builtin_amdgcn_mfma_f32_32x32x16_bf16(a1, b1, acc[1][1], 0, 0, 0);
    }

    float s = 0.f;
#pragma unroll
    for (int a = 0; a < 2; ++a)
#pragma unroll
        for (int b = 0; b < 2; ++b)
#pragma unroll
            for (int e = 0; e < 16; ++e) s += acc[a][b][e];

#pragma unroll
    for (int d = 32; d > 0; d >>= 1) s += __shfl_xor(s, d, 64);
    if (lane == 0) red[wave] = s;
    __syncthreads();
    if (tid == 0)
        ws[WS_DGA + p] = (double)red[0] + (double)red[1] + (double)red[2] + (double)red[3];
}

// ---------------------------------------------------------------------------
// DIAGNOSTIC B: full R3 epilogue (masks, tgt, fmac chains) but the two trans
// ops replaced by identity (lg = a). Dumped to unused ws.
// ---------------------------------------------------------------------------
__global__ __launch_bounds__(256) void diagB_kernel(const float* __restrict__ H,
                                                    const int* __restrict__ tgt,
                                                    double* __restrict__ ws) {
    __shared__ unsigned short As[TILE * BITS];
    __shared__ unsigned short Bs[TILE * BITS];
    __shared__ int tI[TILE];
    __shared__ int tJ[TILE];
    __shared__ float red[12];

    const int tid = threadIdx.x;
    const int p = blockIdx.x;
    int ti, tj; tile_map(p, ti, tj);
    const int i0 = ti * TILE, j0 = tj * TILE;
    const bool diag = (ti == tj);

    if (tid < TILE) { tI[tid] = tgt[i0 + tid]; tJ[tid] = tgt[j0 + tid]; }

#pragma unroll
    for (int it = 0; it < 8; ++it) {
        int idx  = tid + it * 256;
        int half = idx >> 10;
        int lid  = idx & 1023;
        int row  = lid >> 3;
        int c    = lid & 7;
        const float* src = H + (size_t)((half ? j0 : i0) + row) * BITS + c * 8;
        float4 f0 = *(const float4*)src;
        float4 f1 = *(const float4*)(src + 4);
        ushort8v v;
        v[0] = f2bf(f0.x * SQH); v[1] = f2bf(f0.y * SQH);
        v[2] = f2bf(f0.z * SQH); v[3] = f2bf(f0.w * SQH);
        v[4] = f2bf(f1.x * SQH); v[5] = f2bf(f1.y * SQH);
        v[6] = f2bf(f1.z * SQH); v[7] = f2bf(f1.w * SQH);
        unsigned short* dst = half ? Bs : As;
        *(ushort8v*)&dst[row * BITS + ((c ^ (row & 7)) * 8)] = v;
    }
    __syncthreads();

    const int lane = tid & 63, wave = tid >> 6;
    const int wr = wave >> 1, wc = wave & 1;
    const int lrow = lane & 31, hi = lane >> 5;

    f32x16 acc[2][2];
#pragma unroll
    for (int a = 0; a < 2; ++a)
#pragma unroll
        for (int b = 0; b < 2; ++b)
#pragma unroll
            for (int e = 0; e < 16; ++e) acc[a][b][e] = 0.f;

    auto ldfrag = [](const unsigned short* S, int row, int chunk) -> bf16x8 {
        ushort8v r = *(const ushort8v*)&S[row * BITS + ((chunk ^ (row & 7)) * 8)];
        return __builtin_bit_cast(bf16x8, r);
    };

#pragma unroll
    for (int ks = 0; ks < 4; ++ks) {
        const int ch = ks * 2 + hi;
        bf16x8 a0 = ldfrag(As, wr * 64 +      lrow, ch);
        bf16x8 a1 = ldfrag(As, wr * 64 + 32 + lrow, ch);
        bf16x8 b0 = ldfrag(Bs, wc * 64 +      lrow, ch);
        bf16x8 b1 = ldfrag(Bs, wc * 64 + 32 + lrow, ch);
        acc[0][0] = __builtin_amdgcn_mfma_f32_32x32x16_bf16(a0, b0, acc[0][0], 0, 0, 0);
        acc[0][1] = __builtin_amdgcn_mfma_f32_32x32x16_bf16(a0, b1, acc[0][1], 0, 0, 0);
        acc[1][0] = __builtin_amdgcn_mfma_f32_32x32x16_bf16(a1, b0, acc[1][0], 0, 0, 0);
        acc[1][1] = __builtin_amdgcn_mfma_f32_32x32x16_bf16(a1, b1, acc[1][1], 0, 0, 0);
    }

    float s_all = 0.f, s_same = 0.f, t_same = 0.f;
    if (!diag) {
#pragma unroll
        for (int it = 0; it < 2; ++it) {
            int trow[16];
#pragma unroll
            for (int r = 0; r < 16; ++r)
                trow[r] = tI[wr * 64 + it * 32 + (r & 3) + 8 * (r >> 2) + 4 * hi];
#pragma unroll
            for (int jt = 0; jt < 2; ++jt) {
                const int tc = tJ[wc * 64 + jt * 32 + lrow];
                const f32x16& C = it ? (jt ? acc[1][1] : acc[1][0])
                                     : (jt ? acc[0][1] : acc[0][0]);
#pragma unroll
                for (int r = 0; r < 16; ++r) {
                    float a  = C[r];
                    float lg = a;                       // trans replaced by identity
                    s_all += lg;
                    float m = (trow[r] == tc) ? 1.0f : 0.0f;
                    s_same = fmaf(m, lg, s_same);
                    t_same = fmaf(m, a,  t_same);
                }
            }
        }
    } else {
#pragma unroll
        for (int it = 0; it < 2; ++it) {
            int trow[16], lrr[16];
#pragma unroll
            for (int r = 0; r < 16; ++r) {
                lrr[r] = wr * 64 + it * 32 + (r & 3) + 8 * (r >> 2) + 4 * hi;
                trow[r] = tI[lrr[r]];
            }
#pragma unroll
            for (int jt = 0; jt < 2; ++jt) {
                const int lc = wc * 64 + jt * 32 + lrow;
                const int tc = tJ[lc];
                const f32x16& C = it ? (jt ? acc[1][1] : acc[1][0])
                                     : (jt ? acc[0][1] : acc[0][0]);
#pragma unroll
                for (int r = 0; r < 16; ++r) {
                    float a  = C[r];
                    float lg = a;
                    bool v = lc > lrr[r];
                    bool sm = v && (trow[r] == tc);
                    s_all  += v  ? lg : 0.f;
                    s_same += sm ? lg : 0.f;
                    t_same += sm ? a  : 0.f;
                }
            }
        }
    }

#pragma unroll
    for (int d = 32; d > 0; d >>= 1) {
        s_all  += __shfl_xor(s_all,  d, 64);
        s_same += __shfl_xor(s_same, d, 64);
        t_same += __shfl_xor(t_same, d, 64);
    }
    if (lane == 0) { red[wave] = s_all; red[4 + wave] = s_same; red[8 + wave] = t_same; }
    __syncthreads();
    if (tid == 0)
        ws[WS_DGB + p] = (double)red[0] + (double)red[1] + (double)red[2] + (double)red[3]
                       + (double)red[4] + (double)red[5] + (double)red[6] + (double)red[7]
                       + (double)red[8] + (double)red[9] + (double)red[10] + (double)red[11];
}

// ---------------------------------------------------------------------------
// Finalize (unchanged; ignores diag regions).
// ---------------------------------------------------------------------------
__global__ __launch_bounds__(256) void final_kernel(const int* __restrict__ tgt,
                                                    const double* __restrict__ ws,
                                                    float* __restrict__ out) {
    __shared__ int hist[NCLS];
    __shared__ double r0[256], r1[256], r2[256], rc[256];
    const int tid = threadIdx.x;

    for (int i = tid; i < NCLS; i += 256) hist[i] = 0;
    __syncthreads();
    for (int i = tid; i < NPTS; i += 256) atomicAdd(&hist[tgt[i]], 1);
    __syncthreads();

    double a = 0.0, s = 0.0, t = 0.0, c = 0.0;
    for (int i = tid; i < NPAIRS; i += 256) {
        a += ws[i];
        s += ws[NPAIRS + i];
        t += ws[2 * NPAIRS + i];
        c += ws[WS_CLS + i];
    }
    r0[tid] = a; r1[tid] = s; r2[tid] = t; rc[tid] = c;
    __syncthreads();
    for (int sdt = 128; sdt > 0; sdt >>= 1) {
        if (tid < sdt) {
            r0[tid] += r0[tid + sdt];
            r1[tid] += r1[tid + sdt];
            r2[tid] += r2[tid + sdt];
            rc[tid] += rc[tid + sdt];
        }
        __syncthreads();
    }

    if (tid == 0) {
        double n_pos = 0.0;
        for (int k = 0; k < NCLS; k++) {
            double cc = (double)hist[k];
            n_pos += cc * cc;
        }
        const double Nd = (double)NPTS;
        double S1 = n_pos - Nd;
        double S0 = Nd * Nd - n_pos;
        if (S0 == 0.0) S0 = 1.0;
        if (S1 == 0.0) S1 = 1.0;
        const double S = S0 + S1;
        const double sum_lower = (S / S0) * (r0[0] - r1[0]) + (S / S1) * (r1[0] - r2[0]);
        const double count = Nd * (Nd - 1.0) * 0.5;
        const double hash_loss = sum_lower / count;
        const double cls_loss  = rc[0] / Nd;
        const double loss = 1.0 * cls_loss + 0.01 * hash_loss;
        out[0] = (float)hash_loss;
        out[1] = (float)cls_loss;
        out[2] = (float)loss;
    }
}

// ---------------------------------------------------------------------------
extern "C" void kernel_launch(void* const* d_in, const int* in_sizes, int n_in,
                              void* d_out, int out_size, void* d_ws, size_t ws_size,
                              hipStream_t stream) {
    const float* H   = (const float*)d_in[0];
    const float* X   = (const float*)d_in[1];
    const int*   tgt = (const int*)d_in[2];
    float* out = (float*)d_out;
    double* wsd = (double*)d_ws;

    hash_cls_kernel<<<NPAIRS, 256, 0, stream>>>(H, X, tgt, wsd);
    diagA_kernel<<<NPAIRS, 256, 0, stream>>>(H, wsd);
    diagB_kernel<<<NPAIRS, 256, 0, stream>>>(H, tgt, wsd);
    final_kernel<<<1, 256, 0, stream>>>(tgt, wsd, out);
}

// Round 8
// 46.565 us; speedup vs baseline: 1.5321x; 1.5321x over previous
//
#include <hip/hip_runtime.h>
#include <math.h>

#define NPTS   8192
#define BITS   64
#define NCLS   101
#define TILE   128
#define NT     (NPTS / TILE)            // 64
#define NPAIRS (NT * (NT + 1) / 2)      // 2080
#define WS_CLS (3 * NPAIRS)
#define SQH    0.70710678f              // sqrt(0.5): staged h*SQH -> acc = theta

// ws doubles: [0,NPAIRS) sp_all | [N,2N) sp_same | [2N,3N) th_same | [3N,3N+N) cls

typedef short    bf16x8   __attribute__((ext_vector_type(8)));
typedef unsigned short ushort8v __attribute__((ext_vector_type(8)));
typedef float    f32x16   __attribute__((ext_vector_type(16)));

__device__ __forceinline__ unsigned short f2bf(float f) {
    unsigned int u = __float_as_uint(f);
    u += 0x7FFFu + ((u >> 16) & 1u);     // RNE (inputs finite)
    return (unsigned short)(u >> 16);
}

__device__ __forceinline__ void tile_map(int p, int& ti, int& tj) {
    float disc = (2.0f * NT + 1.0f) * (2.0f * NT + 1.0f) - 8.0f * (float)p;
    ti = (int)(((2.0f * NT + 1.0f) - sqrtf(disc)) * 0.5f);
    if (ti < 0) ti = 0;
    if (ti >= NT) ti = NT - 1;
    while (ti > 0 && (ti * NT - ti * (ti - 1) / 2) > p) ti--;
    while ((ti + 1) * NT - (ti + 1) * ti / 2 <= p) ti++;
    tj = ti + (p - (ti * NT - ti * (ti - 1) / 2));
}

// ---------------------------------------------------------------------------
// Fused hash tile + cls rows. Softplus via relu + LDS piecewise-linear LUT of
// g(x)=log1p(exp(-x)) on [0,8] (257 knots, h=1/32) — NO transcendentals in
// the per-element path (trans pipe measured ~60cyc/wave64 instr in R7 diag).
// ---------------------------------------------------------------------------
__global__ __launch_bounds__(256) void hash_cls_kernel(const float* __restrict__ H,
                                                       const float* __restrict__ X,
                                                       const int* __restrict__ tgt,
                                                       double* __restrict__ ws) {
    __shared__ unsigned short As[TILE * BITS];
    __shared__ unsigned short Bs[TILE * BITS];
    __shared__ int tI[TILE];
    __shared__ int tJ[TILE];
    __shared__ float lut[257];
    __shared__ float red[16];

    const int tid = threadIdx.x;
    const int p = blockIdx.x;
    int ti, tj; tile_map(p, ti, tj);
    const int i0 = ti * TILE, j0 = tj * TILE;
    const bool diag = (ti == tj);

    // LUT init (overlaps staging; 257 exp/log1p per block, init-only)
    for (int b = tid; b < 257; b += 256)
        lut[b] = log1pf(__expf(-(float)b * 0.03125f));

    if (tid < TILE) { tI[tid] = tgt[i0 + tid]; tJ[tid] = tgt[j0 + tid]; }

#pragma unroll
    for (int it = 0; it < 8; ++it) {
        int idx  = tid + it * 256;
        int half = idx >> 10;
        int lid  = idx & 1023;
        int row  = lid >> 3;
        int c    = lid & 7;
        const float* src = H + (size_t)((half ? j0 : i0) + row) * BITS + c * 8;
        float4 f0 = *(const float4*)src;
        float4 f1 = *(const float4*)(src + 4);
        ushort8v v;
        v[0] = f2bf(f0.x * SQH); v[1] = f2bf(f0.y * SQH);
        v[2] = f2bf(f0.z * SQH); v[3] = f2bf(f0.w * SQH);
        v[4] = f2bf(f1.x * SQH); v[5] = f2bf(f1.y * SQH);
        v[6] = f2bf(f1.z * SQH); v[7] = f2bf(f1.w * SQH);
        unsigned short* dst = half ? Bs : As;
        *(ushort8v*)&dst[row * BITS + ((c ^ (row & 7)) * 8)] = v;
    }
    __syncthreads();

    const int lane = tid & 63, wave = tid >> 6;
    const int wr = wave >> 1, wc = wave & 1;
    const int lrow = lane & 31, hi = lane >> 5;

    f32x16 acc[2][2];
#pragma unroll
    for (int a = 0; a < 2; ++a)
#pragma unroll
        for (int b = 0; b < 2; ++b)
#pragma unroll
            for (int e = 0; e < 16; ++e) acc[a][b][e] = 0.f;

    auto ldfrag = [](const unsigned short* S, int row, int chunk) -> bf16x8 {
        ushort8v r = *(const ushort8v*)&S[row * BITS + ((chunk ^ (row & 7)) * 8)];
        return __builtin_bit_cast(bf16x8, r);
    };

#pragma unroll
    for (int ks = 0; ks < 4; ++ks) {
        const int ch = ks * 2 + hi;
        bf16x8 a0 = ldfrag(As, wr * 64 +      lrow, ch);
        bf16x8 a1 = ldfrag(As, wr * 64 + 32 + lrow, ch);
        bf16x8 b0 = ldfrag(Bs, wc * 64 +      lrow, ch);
        bf16x8 b1 = ldfrag(Bs, wc * 64 + 32 + lrow, ch);
        acc[0][0] = __builtin_amdgcn_mfma_f32_32x32x16_bf16(a0, b0, acc[0][0], 0, 0, 0);
        acc[0][1] = __builtin_amdgcn_mfma_f32_32x32x16_bf16(a0, b1, acc[0][1], 0, 0, 0);
        acc[1][0] = __builtin_amdgcn_mfma_f32_32x32x16_bf16(a1, b0, acc[1][0], 0, 0, 0);
        acc[1][1] = __builtin_amdgcn_mfma_f32_32x32x16_bf16(a1, b1, acc[1][1], 0, 0, 0);
    }

    // softplus(a) = max(a,0) + lut-lerp(|a|)  — pure VALU + one ds_read2_b32
    auto softplus = [&](float a) -> float {
        float x = fabsf(a);
        float u = fminf(x * 32.0f, 255.0f);
        int   i = (int)u;
        float d = u - (float)i;
        float g0 = lut[i], g1 = lut[i + 1];
        return fmaxf(a, 0.f) + fmaf(g1 - g0, d, g0);
    };

    float s_all = 0.f, s_same = 0.f, t_same = 0.f;
    if (!diag) {
#pragma unroll
        for (int it = 0; it < 2; ++it) {
            int trow[16];
#pragma unroll
            for (int r = 0; r < 16; ++r)
                trow[r] = tI[wr * 64 + it * 32 + (r & 3) + 8 * (r >> 2) + 4 * hi];
#pragma unroll
            for (int jt = 0; jt < 2; ++jt) {
                const int tc = tJ[wc * 64 + jt * 32 + lrow];
                const f32x16& C = it ? (jt ? acc[1][1] : acc[1][0])
                                     : (jt ? acc[0][1] : acc[0][0]);
#pragma unroll
                for (int r = 0; r < 16; ++r) {
                    float a  = C[r];
                    float lg = softplus(a);
                    s_all += lg;
                    float m = (trow[r] == tc) ? 1.0f : 0.0f;
                    s_same = fmaf(m, lg, s_same);
                    t_same = fmaf(m, a,  t_same);
                }
            }
        }
    } else {
#pragma unroll
        for (int it = 0; it < 2; ++it) {
            int trow[16], lrr[16];
#pragma unroll
            for (int r = 0; r < 16; ++r) {
                lrr[r] = wr * 64 + it * 32 + (r & 3) + 8 * (r >> 2) + 4 * hi;
                trow[r] = tI[lrr[r]];
            }
#pragma unroll
            for (int jt = 0; jt < 2; ++jt) {
                const int lc = wc * 64 + jt * 32 + lrow;
                const int tc = tJ[lc];
                const f32x16& C = it ? (jt ? acc[1][1] : acc[1][0])
                                     : (jt ? acc[0][1] : acc[0][0]);
#pragma unroll
                for (int r = 0; r < 16; ++r) {
                    float a  = C[r];
                    float lg = softplus(a);
                    bool v  = lc > lrr[r];
                    bool sm = v && (trow[r] == tc);
                    s_all  += v  ? lg : 0.f;
                    s_same += sm ? lg : 0.f;
                    t_same += sm ? a  : 0.f;
                }
            }
        }
    }

#pragma unroll
    for (int d = 32; d > 0; d >>= 1) {
        s_all  += __shfl_xor(s_all,  d, 64);
        s_same += __shfl_xor(s_same, d, 64);
        t_same += __shfl_xor(t_same, d, 64);
    }
    if (lane == 0) { red[wave] = s_all; red[4 + wave] = s_same; red[8 + wave] = t_same; }

    {   // fused cls rows (101 logits; trans count here is negligible)
        const int row = p * 4 + wave;
        float nll = 0.f;
        if (row < NPTS) {
            const float* x = X + (size_t)row * NCLS;
            float x1 = x[lane];
            float x2 = (lane + 64 < NCLS) ? x[lane + 64] : -INFINITY;
            float m = fmaxf(x1, x2);
#pragma unroll
            for (int d = 32; d > 0; d >>= 1) m = fmaxf(m, __shfl_xor(m, d, 64));
            float e = __expf(x1 - m) + ((lane + 64 < NCLS) ? __expf(x2 - m) : 0.f);
#pragma unroll
            for (int d = 32; d > 0; d >>= 1) e += __shfl_xor(e, d, 64);
            if (lane == 0) nll = m + __logf(e) - x[tgt[row]];
        }
        if (lane == 0) red[12 + wave] = nll;
    }
    __syncthreads();
    if (tid == 0) {
        ws[p]              = (double)red[0]  + (double)red[1]  + (double)red[2]  + (double)red[3];
        ws[NPAIRS + p]     = (double)red[4]  + (double)red[5]  + (double)red[6]  + (double)red[7];
        ws[2 * NPAIRS + p] = (double)red[8]  + (double)red[9]  + (double)red[10] + (double)red[11];
        ws[WS_CLS + p]     = (double)red[12] + (double)red[13] + (double)red[14] + (double)red[15];
    }
}

// ---------------------------------------------------------------------------
// Finalize: histogram -> S0/S1 weights; double reduction; 3 scalars.
// ---------------------------------------------------------------------------
__global__ __launch_bounds__(256) void final_kernel(const int* __restrict__ tgt,
                                                    const double* __restrict__ ws,
                                                    float* __restrict__ out) {
    __shared__ int hist[NCLS];
    __shared__ double r0[256], r1[256], r2[256], rc[256];
    const int tid = threadIdx.x;

    for (int i = tid; i < NCLS; i += 256) hist[i] = 0;
    __syncthreads();
    for (int i = tid; i < NPTS; i += 256) atomicAdd(&hist[tgt[i]], 1);
    __syncthreads();

    double a = 0.0, s = 0.0, t = 0.0, c = 0.0;
    for (int i = tid; i < NPAIRS; i += 256) {
        a += ws[i];
        s += ws[NPAIRS + i];
        t += ws[2 * NPAIRS + i];
        c += ws[WS_CLS + i];
    }
    r0[tid] = a; r1[tid] = s; r2[tid] = t; rc[tid] = c;
    __syncthreads();
    for (int sdt = 128; sdt > 0; sdt >>= 1) {
        if (tid < sdt) {
            r0[tid] += r0[tid + sdt];
            r1[tid] += r1[tid + sdt];
            r2[tid] += r2[tid + sdt];
            rc[tid] += rc[tid + sdt];
        }
        __syncthreads();
    }

    if (tid == 0) {
        double n_pos = 0.0;
        for (int k = 0; k < NCLS; k++) {
            double cc = (double)hist[k];
            n_pos += cc * cc;
        }
        const double Nd = (double)NPTS;
        double S1 = n_pos - Nd;
        double S0 = Nd * Nd - n_pos;
        if (S0 == 0.0) S0 = 1.0;
        if (S1 == 0.0) S1 = 1.0;
        const double S = S0 + S1;
        const double sum_lower = (S / S0) * (r0[0] - r1[0]) + (S / S1) * (r1[0] - r2[0]);
        const double count = Nd * (Nd - 1.0) * 0.5;
        const double hash_loss = sum_lower / count;
        const double cls_loss  = rc[0] / Nd;
        const double loss = 1.0 * cls_loss + 0.01 * hash_loss;
        out[0] = (float)hash_loss;
        out[1] = (float)cls_loss;
        out[2] = (float)loss;
    }
}

// ---------------------------------------------------------------------------
extern "C" void kernel_launch(void* const* d_in, const int* in_sizes, int n_in,
                              void* d_out, int out_size, void* d_ws, size_t ws_size,
                              hipStream_t stream) {
    const float* H   = (const float*)d_in[0];
    const float* X   = (const float*)d_in[1];
    const int*   tgt = (const int*)d_in[2];
    float* out = (float*)d_out;
    double* wsd = (double*)d_ws;

    hash_cls_kernel<<<NPAIRS, 256, 0, stream>>>(H, X, tgt, wsd);
    final_kernel<<<1, 256, 0, stream>>>(tgt, wsd, out);
}

// Round 9
// 46.267 us; speedup vs baseline: 1.5420x; 1.0064x over previous
//
#include <hip/hip_runtime.h>
#include <math.h>

#define NPTS   8192
#define BITS   64
#define NCLS   101
#define TILE   128
#define NT     (NPTS / TILE)            // 64
#define NPAIRS (NT * (NT + 1) / 2)      // 2080
#define WS_CLS (3 * NPAIRS)
#define SCALE  0.84932184f              // sqrt(0.5*log2 e): acc = t = theta*log2(e)
#define LN2    0.6931471805599453

// ws doubles: [0,N) sp_all(log2 units) | [N,2N) sp_same | [2N,3N) t_same | [3N,4N) cls

typedef short    bf16x8   __attribute__((ext_vector_type(8)));
typedef unsigned short ushort8v __attribute__((ext_vector_type(8)));
typedef float    f32x16   __attribute__((ext_vector_type(16)));

__device__ __forceinline__ unsigned short f2bf(float f) {
    unsigned int u = __float_as_uint(f);
    u += 0x7FFFu + ((u >> 16) & 1u);     // RNE (inputs finite)
    return (unsigned short)(u >> 16);
}

__device__ __forceinline__ void tile_map(int p, int& ti, int& tj) {
    float disc = (2.0f * NT + 1.0f) * (2.0f * NT + 1.0f) - 8.0f * (float)p;
    ti = (int)(((2.0f * NT + 1.0f) - sqrtf(disc)) * 0.5f);
    if (ti < 0) ti = 0;
    if (ti >= NT) ti = NT - 1;
    while (ti > 0 && (ti * NT - ti * (ti - 1) / 2) > p) ti--;
    while ((ti + 1) * NT - (ti + 1) * ti / 2 <= p) ti++;
    tj = ti + (p - (ti * NT - ti * (ti - 1) / 2));
}

// log2(1 + 2^t) in PURE full-rate VALU (no trans, no LDS):
//   v = max(-|t|, -16);  2^v by floor/fract + cubic(2^f) + exponent-bit build;
//   log2(1+u) by deg-4 minimax on (0,1] (Chebyshev-derived, abs err ~1e-4).
__device__ __forceinline__ float sp2(float t) {
    float v  = fmaxf(0.0f - fabsf(t), -16.0f);   // [-16, 0]
    float fl = floorf(v);
    float f  = v - fl;                            // [0,1)
    float p  = fmaf(f, 0.0790209f, 0.2251075f);   // 2^f cubic minimax
    p = fmaf(f, p, 0.6958092f);
    p = fmaf(f, p, 0.9999252f);
    int   ie = (int)fl;                           // [-16, 0]
    float sc = __int_as_float((ie + 127) << 23);  // 2^ie (no denormals)
    float u  = p * sc;                            // 2^{-|t|} in (0,1]
    float q  = fmaf(u, -0.0799600f, 0.3153610f);  // log2(1+u) deg-4
    q = fmaf(u, q, -0.6728620f);
    q = fmaf(u, q, 1.4372850f);
    q = fmaf(u, q, 0.0001746f);
    return fmaxf(t, 0.0f) + q;
}

// ---------------------------------------------------------------------------
// Fused hash tile + cls rows (R3 structure; epilogue = VALU-only softplus).
// ---------------------------------------------------------------------------
__global__ __launch_bounds__(256) void hash_cls_kernel(const float* __restrict__ H,
                                                       const float* __restrict__ X,
                                                       const int* __restrict__ tgt,
                                                       double* __restrict__ ws) {
    __shared__ unsigned short As[TILE * BITS];
    __shared__ unsigned short Bs[TILE * BITS];
    __shared__ int tI[TILE];
    __shared__ int tJ[TILE];
    __shared__ float red[16];

    const int tid = threadIdx.x;
    const int p = blockIdx.x;
    int ti, tj; tile_map(p, ti, tj);
    const int i0 = ti * TILE, j0 = tj * TILE;
    const bool diag = (ti == tj);

    if (tid < TILE) { tI[tid] = tgt[i0 + tid]; tJ[tid] = tgt[j0 + tid]; }

#pragma unroll
    for (int it = 0; it < 8; ++it) {
        int idx  = tid + it * 256;
        int half = idx >> 10;
        int lid  = idx & 1023;
        int row  = lid >> 3;
        int c    = lid & 7;
        const float* src = H + (size_t)((half ? j0 : i0) + row) * BITS + c * 8;
        float4 f0 = *(const float4*)src;
        float4 f1 = *(const float4*)(src + 4);
        ushort8v v;
        v[0] = f2bf(f0.x * SCALE); v[1] = f2bf(f0.y * SCALE);
        v[2] = f2bf(f0.z * SCALE); v[3] = f2bf(f0.w * SCALE);
        v[4] = f2bf(f1.x * SCALE); v[5] = f2bf(f1.y * SCALE);
        v[6] = f2bf(f1.z * SCALE); v[7] = f2bf(f1.w * SCALE);
        unsigned short* dst = half ? Bs : As;
        *(ushort8v*)&dst[row * BITS + ((c ^ (row & 7)) * 8)] = v;
    }
    __syncthreads();

    const int lane = tid & 63, wave = tid >> 6;
    const int wr = wave >> 1, wc = wave & 1;
    const int lrow = lane & 31, hi = lane >> 5;

    f32x16 acc[2][2];
#pragma unroll
    for (int a = 0; a < 2; ++a)
#pragma unroll
        for (int b = 0; b < 2; ++b)
#pragma unroll
            for (int e = 0; e < 16; ++e) acc[a][b][e] = 0.f;

    auto ldfrag = [](const unsigned short* S, int row, int chunk) -> bf16x8 {
        ushort8v r = *(const ushort8v*)&S[row * BITS + ((chunk ^ (row & 7)) * 8)];
        return __builtin_bit_cast(bf16x8, r);
    };

#pragma unroll
    for (int ks = 0; ks < 4; ++ks) {
        const int ch = ks * 2 + hi;
        bf16x8 a0 = ldfrag(As, wr * 64 +      lrow, ch);
        bf16x8 a1 = ldfrag(As, wr * 64 + 32 + lrow, ch);
        bf16x8 b0 = ldfrag(Bs, wc * 64 +      lrow, ch);
        bf16x8 b1 = ldfrag(Bs, wc * 64 + 32 + lrow, ch);
        acc[0][0] = __builtin_amdgcn_mfma_f32_32x32x16_bf16(a0, b0, acc[0][0], 0, 0, 0);
        acc[0][1] = __builtin_amdgcn_mfma_f32_32x32x16_bf16(a0, b1, acc[0][1], 0, 0, 0);
        acc[1][0] = __builtin_amdgcn_mfma_f32_32x32x16_bf16(a1, b0, acc[1][0], 0, 0, 0);
        acc[1][1] = __builtin_amdgcn_mfma_f32_32x32x16_bf16(a1, b1, acc[1][1], 0, 0, 0);
    }

    float s_all = 0.f, s_same = 0.f, t_same = 0.f;
    if (!diag) {
#pragma unroll
        for (int it = 0; it < 2; ++it) {
            int trow[16];
#pragma unroll
            for (int r = 0; r < 16; ++r)
                trow[r] = tI[wr * 64 + it * 32 + (r & 3) + 8 * (r >> 2) + 4 * hi];
#pragma unroll
            for (int jt = 0; jt < 2; ++jt) {
                const int tc = tJ[wc * 64 + jt * 32 + lrow];
                const f32x16& C = it ? (jt ? acc[1][1] : acc[1][0])
                                     : (jt ? acc[0][1] : acc[0][0]);
#pragma unroll
                for (int r = 0; r < 16; ++r) {
                    float t  = C[r];                 // theta*log2e
                    float lg = sp2(t);               // softplus/ln2
                    s_all += lg;
                    float m = (trow[r] == tc) ? 1.0f : 0.0f;
                    s_same = fmaf(m, lg, s_same);
                    t_same = fmaf(m, t,  t_same);
                }
            }
        }
    } else {
#pragma unroll
        for (int it = 0; it < 2; ++it) {
            int trow[16], lrr[16];
#pragma unroll
            for (int r = 0; r < 16; ++r) {
                lrr[r] = wr * 64 + it * 32 + (r & 3) + 8 * (r >> 2) + 4 * hi;
                trow[r] = tI[lrr[r]];
            }
#pragma unroll
            for (int jt = 0; jt < 2; ++jt) {
                const int lc = wc * 64 + jt * 32 + lrow;
                const int tc = tJ[lc];
                const f32x16& C = it ? (jt ? acc[1][1] : acc[1][0])
                                     : (jt ? acc[0][1] : acc[0][0]);
#pragma unroll
                for (int r = 0; r < 16; ++r) {
                    float t  = C[r];
                    float lg = sp2(t);
                    bool v  = lc > lrr[r];
                    bool sm = v && (trow[r] == tc);
                    s_all  += v  ? lg : 0.f;
                    s_same += sm ? lg : 0.f;
                    t_same += sm ? t  : 0.f;
                }
            }
        }
    }

#pragma unroll
    for (int d = 32; d > 0; d >>= 1) {
        s_all  += __shfl_xor(s_all,  d, 64);
        s_same += __shfl_xor(s_same, d, 64);
        t_same += __shfl_xor(t_same, d, 64);
    }
    if (lane == 0) { red[wave] = s_all; red[4 + wave] = s_same; red[8 + wave] = t_same; }

    {   // fused cls rows (trans here: ~3 instrs/row — negligible)
        const int row = p * 4 + wave;
        float nll = 0.f;
        if (row < NPTS) {
            const float* x = X + (size_t)row * NCLS;
            float x1 = x[lane];
            float x2 = (lane + 64 < NCLS) ? x[lane + 64] : -INFINITY;
            float m = fmaxf(x1, x2);
#pragma unroll
            for (int d = 32; d > 0; d >>= 1) m = fmaxf(m, __shfl_xor(m, d, 64));
            float e = __expf(x1 - m) + ((lane + 64 < NCLS) ? __expf(x2 - m) : 0.f);
#pragma unroll
            for (int d = 32; d > 0; d >>= 1) e += __shfl_xor(e, d, 64);
            if (lane == 0) nll = m + __logf(e) - x[tgt[row]];
        }
        if (lane == 0) red[12 + wave] = nll;
    }
    __syncthreads();
    if (tid == 0) {
        ws[p]              = (double)red[0]  + (double)red[1]  + (double)red[2]  + (double)red[3];
        ws[NPAIRS + p]     = (double)red[4]  + (double)red[5]  + (double)red[6]  + (double)red[7];
        ws[2 * NPAIRS + p] = (double)red[8]  + (double)red[9]  + (double)red[10] + (double)red[11];
        ws[WS_CLS + p]     = (double)red[12] + (double)red[13] + (double)red[14] + (double)red[15];
    }
}

// ---------------------------------------------------------------------------
// Finalize: histogram -> S0/S1 weights; double reduction; ln2 fold here.
// ---------------------------------------------------------------------------
__global__ __launch_bounds__(256) void final_kernel(const int* __restrict__ tgt,
                                                    const double* __restrict__ ws,
                                                    float* __restrict__ out) {
    __shared__ int hist[NCLS];
    __shared__ double r0[256], r1[256], r2[256], rc[256];
    const int tid = threadIdx.x;

    for (int i = tid; i < NCLS; i += 256) hist[i] = 0;
    __syncthreads();
    for (int i = tid; i < NPTS; i += 256) atomicAdd(&hist[tgt[i]], 1);
    __syncthreads();

    double a = 0.0, s = 0.0, t = 0.0, c = 0.0;
    for (int i = tid; i < NPAIRS; i += 256) {
        a += ws[i];
        s += ws[NPAIRS + i];
        t += ws[2 * NPAIRS + i];
        c += ws[WS_CLS + i];
    }
    r0[tid] = a; r1[tid] = s; r2[tid] = t; rc[tid] = c;
    __syncthreads();
    for (int sdt = 128; sdt > 0; sdt >>= 1) {
        if (tid < sdt) {
            r0[tid] += r0[tid + sdt];
            r1[tid] += r1[tid + sdt];
            r2[tid] += r2[tid + sdt];
            rc[tid] += rc[tid + sdt];
        }
        __syncthreads();
    }

    if (tid == 0) {
        double n_pos = 0.0;
        for (int k = 0; k < NCLS; k++) {
            double cc = (double)hist[k];
            n_pos += cc * cc;
        }
        const double Nd = (double)NPTS;
        double S1 = n_pos - Nd;
        double S0 = Nd * Nd - n_pos;
        if (S0 == 0.0) S0 = 1.0;
        if (S1 == 0.0) S1 = 1.0;
        const double S = S0 + S1;
        // partials in log2 / log2e units -> single ln2 factor here
        const double sum_lower =
            ((S / S0) * (r0[0] - r1[0]) + (S / S1) * (r1[0] - r2[0])) * LN2;
        const double count = Nd * (Nd - 1.0) * 0.5;
        const double hash_loss = sum_lower / count;
        const double cls_loss  = rc[0] / Nd;
        const double loss = 1.0 * cls_loss + 0.01 * hash_loss;
        out[0] = (float)hash_loss;
        out[1] = (float)cls_loss;
        out[2] = (float)loss;
    }
}

// ---------------------------------------------------------------------------
extern "C" void kernel_launch(void* const* d_in, const int* in_sizes, int n_in,
                              void* d_out, int out_size, void* d_ws, size_t ws_size,
                              hipStream_t stream) {
    const float* H   = (const float*)d_in[0];
    const float* X   = (const float*)d_in[1];
    const int*   tgt = (const int*)d_in[2];
    float* out = (float*)d_out;
    double* wsd = (double*)d_ws;

    hash_cls_kernel<<<NPAIRS, 256, 0, stream>>>(H, X, tgt, wsd);
    final_kernel<<<1, 256, 0, stream>>>(tgt, wsd, out);
}

// Round 10
// 42.750 us; speedup vs baseline: 1.6688x; 1.0823x over previous
//
#include <hip/hip_runtime.h>
#include <math.h>

#define NPTS   8192
#define BITS   64
#define NCLS   101
#define TILE   128
#define NT     (NPTS / TILE)            // 64
#define NPAIRS (NT * (NT + 1) / 2)      // 2080
#define WS_CLS (3 * NPAIRS)
#define SCALE  0.84932184f              // sqrt(0.5*log2 e): acc = t = theta*log2(e)
#define LN2    0.6931471805599453
#define SCH_BITS 1064872494             // (127<<23) - 0.0573*2^23 : mean-zero Schraudolph

// ws doubles: [0,N) sp_all(log2 units) | [N,2N) sp_same | [2N,3N) t_same | [3N,4N) cls

typedef short    bf16x8   __attribute__((ext_vector_type(8)));
typedef unsigned short ushort8v __attribute__((ext_vector_type(8)));
typedef float    f32x16   __attribute__((ext_vector_type(16)));

__device__ __forceinline__ unsigned short f2bf(float f) {
    unsigned int u = __float_as_uint(f);
    u += 0x7FFFu + ((u >> 16) & 1u);     // RNE (inputs finite)
    return (unsigned short)(u >> 16);
}

__device__ __forceinline__ float flog2(float x) {
    float r; asm("v_log_f32 %0, %1" : "=v"(r) : "v"(x)); return r;
}

__device__ __forceinline__ void tile_map(int p, int& ti, int& tj) {
    float disc = (2.0f * NT + 1.0f) * (2.0f * NT + 1.0f) - 8.0f * (float)p;
    ti = (int)(((2.0f * NT + 1.0f) - sqrtf(disc)) * 0.5f);
    if (ti < 0) ti = 0;
    if (ti >= NT) ti = NT - 1;
    while (ti > 0 && (ti * NT - ti * (ti - 1) / 2) > p) ti--;
    while ((ti + 1) * NT - (ti + 1) * ti / 2 <= p) ti++;
    tj = ti + (p - (ti * NT - ti * (ti - 1) / 2));
}

// Schraudolph 2^v (v <= 0), mean-zero-tuned; pure full-rate VALU (3 ops).
__device__ __forceinline__ float exp2_fast(float v) {
    int ib = (int)(v * 8388608.0f);           // v * 2^23 (trunc)
    return __int_as_float(ib + SCH_BITS);
}

// ---------------------------------------------------------------------------
// Fused hash tile + cls rows. Epilogue: softplus via log-of-product —
// per element only {min,clamp,mul,cvt,iadd,add,2 mul,max,add,+masked fmas};
// log2 taken ONCE per thread per accumulator (2 v_log total).
// ---------------------------------------------------------------------------
__global__ __launch_bounds__(256) void hash_cls_kernel(const float* __restrict__ H,
                                                       const float* __restrict__ X,
                                                       const int* __restrict__ tgt,
                                                       double* __restrict__ ws) {
    __shared__ unsigned short As[TILE * BITS];
    __shared__ unsigned short Bs[TILE * BITS];
    __shared__ int tI[TILE];
    __shared__ int tJ[TILE];
    __shared__ float red[16];

    const int tid = threadIdx.x;
    const int p = blockIdx.x;
    int ti, tj; tile_map(p, ti, tj);
    const int i0 = ti * TILE, j0 = tj * TILE;
    const bool diag = (ti == tj);

    if (tid < TILE) { tI[tid] = tgt[i0 + tid]; tJ[tid] = tgt[j0 + tid]; }

#pragma unroll
    for (int it = 0; it < 8; ++it) {
        int idx  = tid + it * 256;
        int half = idx >> 10;
        int lid  = idx & 1023;
        int row  = lid >> 3;
        int c    = lid & 7;
        const float* src = H + (size_t)((half ? j0 : i0) + row) * BITS + c * 8;
        float4 f0 = *(const float4*)src;
        float4 f1 = *(const float4*)(src + 4);
        ushort8v v;
        v[0] = f2bf(f0.x * SCALE); v[1] = f2bf(f0.y * SCALE);
        v[2] = f2bf(f0.z * SCALE); v[3] = f2bf(f0.w * SCALE);
        v[4] = f2bf(f1.x * SCALE); v[5] = f2bf(f1.y * SCALE);
        v[6] = f2bf(f1.z * SCALE); v[7] = f2bf(f1.w * SCALE);
        unsigned short* dst = half ? Bs : As;
        *(ushort8v*)&dst[row * BITS + ((c ^ (row & 7)) * 8)] = v;
    }
    __syncthreads();

    const int lane = tid & 63, wave = tid >> 6;
    const int wr = wave >> 1, wc = wave & 1;
    const int lrow = lane & 31, hi = lane >> 5;

    f32x16 acc[2][2];
#pragma unroll
    for (int a = 0; a < 2; ++a)
#pragma unroll
        for (int b = 0; b < 2; ++b)
#pragma unroll
            for (int e = 0; e < 16; ++e) acc[a][b][e] = 0.f;

    auto ldfrag = [](const unsigned short* S, int row, int chunk) -> bf16x8 {
        ushort8v r = *(const ushort8v*)&S[row * BITS + ((chunk ^ (row & 7)) * 8)];
        return __builtin_bit_cast(bf16x8, r);
    };

#pragma unroll
    for (int ks = 0; ks < 4; ++ks) {
        const int ch = ks * 2 + hi;
        bf16x8 a0 = ldfrag(As, wr * 64 +      lrow, ch);
        bf16x8 a1 = ldfrag(As, wr * 64 + 32 + lrow, ch);
        bf16x8 b0 = ldfrag(Bs, wc * 64 +      lrow, ch);
        bf16x8 b1 = ldfrag(Bs, wc * 64 + 32 + lrow, ch);
        acc[0][0] = __builtin_amdgcn_mfma_f32_32x32x16_bf16(a0, b0, acc[0][0], 0, 0, 0);
        acc[0][1] = __builtin_amdgcn_mfma_f32_32x32x16_bf16(a0, b1, acc[0][1], 0, 0, 0);
        acc[1][0] = __builtin_amdgcn_mfma_f32_32x32x16_bf16(a1, b0, acc[1][0], 0, 0, 0);
        acc[1][1] = __builtin_amdgcn_mfma_f32_32x32x16_bf16(a1, b1, acc[1][1], 0, 0, 0);
    }

    float prod_all = 1.f, prod_same = 1.f;
    float s_relu = 0.f, s_relu_s = 0.f, t_sum_s = 0.f;

    if (!diag) {
#pragma unroll
        for (int it = 0; it < 2; ++it) {
            int trow[16];
#pragma unroll
            for (int r = 0; r < 16; ++r)
                trow[r] = tI[wr * 64 + it * 32 + (r & 3) + 8 * (r >> 2) + 4 * hi];
#pragma unroll
            for (int jt = 0; jt < 2; ++jt) {
                const int tc = tJ[wc * 64 + jt * 32 + lrow];
                const f32x16& C = it ? (jt ? acc[1][1] : acc[1][0])
                                     : (jt ? acc[0][1] : acc[0][0]);
#pragma unroll
                for (int r = 0; r < 16; ++r) {
                    float t = C[r];                           // theta*log2e
                    float v = fmaxf(fminf(t, 0.f - t), -126.f); // -|t|, clamped
                    float u = exp2_fast(v);                   // ~2^{-|t|}
                    float w = 1.0f + u;
                    bool  m = (trow[r] == tc);
                    prod_all  *= w;
                    prod_same *= m ? w : 1.0f;
                    float rl = fmaxf(t, 0.f);
                    s_relu   += rl;
                    s_relu_s += m ? rl : 0.f;
                    t_sum_s  += m ? t  : 0.f;
                }
            }
        }
    } else {
#pragma unroll
        for (int it = 0; it < 2; ++it) {
            int trow[16], lrr[16];
#pragma unroll
            for (int r = 0; r < 16; ++r) {
                lrr[r] = wr * 64 + it * 32 + (r & 3) + 8 * (r >> 2) + 4 * hi;
                trow[r] = tI[lrr[r]];
            }
#pragma unroll
            for (int jt = 0; jt < 2; ++jt) {
                const int lc = wc * 64 + jt * 32 + lrow;
                const int tc = tJ[lc];
                const f32x16& C = it ? (jt ? acc[1][1] : acc[1][0])
                                     : (jt ? acc[0][1] : acc[0][0]);
#pragma unroll
                for (int r = 0; r < 16; ++r) {
                    float t = C[r];
                    float v = fmaxf(fminf(t, 0.f - t), -126.f);
                    float u = exp2_fast(v);
                    float w = 1.0f + u;
                    bool  vd = lc > lrr[r];
                    bool  m  = vd && (trow[r] == tc);
                    prod_all  *= vd ? w : 1.0f;
                    prod_same *= m  ? w : 1.0f;
                    float rl = fmaxf(t, 0.f);
                    s_relu   += vd ? rl : 0.f;
                    s_relu_s += m  ? rl : 0.f;
                    t_sum_s  += m  ? t  : 0.f;
                }
            }
        }
    }

    float s_all  = s_relu   + flog2(prod_all);    // softplus/ln2 totals
    float s_same = s_relu_s + flog2(prod_same);
    float t_same = t_sum_s;

#pragma unroll
    for (int d = 32; d > 0; d >>= 1) {
        s_all  += __shfl_xor(s_all,  d, 64);
        s_same += __shfl_xor(s_same, d, 64);
        t_same += __shfl_xor(t_same, d, 64);
    }
    if (lane == 0) { red[wave] = s_all; red[4 + wave] = s_same; red[8 + wave] = t_same; }

    {   // fused cls rows
        const int row = p * 4 + wave;
        float nll = 0.f;
        if (row < NPTS) {
            const float* x = X + (size_t)row * NCLS;
            float x1 = x[lane];
            float x2 = (lane + 64 < NCLS) ? x[lane + 64] : -INFINITY;
            float m = fmaxf(x1, x2);
#pragma unroll
            for (int d = 32; d > 0; d >>= 1) m = fmaxf(m, __shfl_xor(m, d, 64));
            float e = __expf(x1 - m) + ((lane + 64 < NCLS) ? __expf(x2 - m) : 0.f);
#pragma unroll
            for (int d = 32; d > 0; d >>= 1) e += __shfl_xor(e, d, 64);
            if (lane == 0) nll = m + __logf(e) - x[tgt[row]];
        }
        if (lane == 0) red[12 + wave] = nll;
    }
    __syncthreads();
    if (tid == 0) {
        ws[p]              = (double)red[0]  + (double)red[1]  + (double)red[2]  + (double)red[3];
        ws[NPAIRS + p]     = (double)red[4]  + (double)red[5]  + (double)red[6]  + (double)red[7];
        ws[2 * NPAIRS + p] = (double)red[8]  + (double)red[9]  + (double)red[10] + (double)red[11];
        ws[WS_CLS + p]     = (double)red[12] + (double)red[13] + (double)red[14] + (double)red[15];
    }
}

// ---------------------------------------------------------------------------
// Finalize: histogram -> S0/S1 weights; double reduction; ln2 fold here.
// ---------------------------------------------------------------------------
__global__ __launch_bounds__(256) void final_kernel(const int* __restrict__ tgt,
                                                    const double* __restrict__ ws,
                                                    float* __restrict__ out) {
    __shared__ int hist[NCLS];
    __shared__ double r0[256], r1[256], r2[256], rc[256];
    const int tid = threadIdx.x;

    for (int i = tid; i < NCLS; i += 256) hist[i] = 0;
    __syncthreads();
    for (int i = tid; i < NPTS; i += 256) atomicAdd(&hist[tgt[i]], 1);
    __syncthreads();

    double a = 0.0, s = 0.0, t = 0.0, c = 0.0;
    for (int i = tid; i < NPAIRS; i += 256) {
        a += ws[i];
        s += ws[NPAIRS + i];
        t += ws[2 * NPAIRS + i];
        c += ws[WS_CLS + i];
    }
    r0[tid] = a; r1[tid] = s; r2[tid] = t; rc[tid] = c;
    __syncthreads();
    for (int sdt = 128; sdt > 0; sdt >>= 1) {
        if (tid < sdt) {
            r0[tid] += r0[tid + sdt];
            r1[tid] += r1[tid + sdt];
            r2[tid] += r2[tid + sdt];
            rc[tid] += rc[tid + sdt];
        }
        __syncthreads();
    }

    if (tid == 0) {
        double n_pos = 0.0;
        for (int k = 0; k < NCLS; k++) {
            double cc = (double)hist[k];
            n_pos += cc * cc;
        }
        const double Nd = (double)NPTS;
        double S1 = n_pos - Nd;
        double S0 = Nd * Nd - n_pos;
        if (S0 == 0.0) S0 = 1.0;
        if (S1 == 0.0) S1 = 1.0;
        const double S = S0 + S1;
        // partials in log2 / log2e units -> single ln2 factor here
        const double sum_lower =
            ((S / S0) * (r0[0] - r1[0]) + (S / S1) * (r1[0] - r2[0])) * LN2;
        const double count = Nd * (Nd - 1.0) * 0.5;
        const double hash_loss = sum_lower / count;
        const double cls_loss  = rc[0] / Nd;
        const double loss = 1.0 * cls_loss + 0.01 * hash_loss;
        out[0] = (float)hash_loss;
        out[1] = (float)cls_loss;
        out[2] = (float)loss;
    }
}

// ---------------------------------------------------------------------------
extern "C" void kernel_launch(void* const* d_in, const int* in_sizes, int n_in,
                              void* d_out, int out_size, void* d_ws, size_t ws_size,
                              hipStream_t stream) {
    const float* H   = (const float*)d_in[0];
    const float* X   = (const float*)d_in[1];
    const int*   tgt = (const int*)d_in[2];
    float* out = (float*)d_out;
    double* wsd = (double*)d_ws;

    hash_cls_kernel<<<NPAIRS, 256, 0, stream>>>(H, X, tgt, wsd);
    final_kernel<<<1, 256, 0, stream>>>(tgt, wsd, out);
}